// Round 1
// baseline (591.655 us; speedup 1.0000x reference)
//
#include <hip/hip_runtime.h>

#define B_ 256
#define K_ 10
#define I_ 1152
#define O_ 16
#define C_ 8
#define BKO (B_*K_*O_)   // 40960

// ---------------------------------------------------------------------------
// s_kernel: s_part[p][b][k][o] = sum_{i in part p} c(b,k,i) * sum_c w[k,i,o,c]*x[b,i,c]
// cbuf == nullptr -> c = 1/K (pass 1).
// grid: (320, 3): blockIdx.x -> k = x>>5, b0 = (x&31)*8 ; blockIdx.y = i-partition (384 i's each)
// block: 256 threads: o = t&15, ig = t>>4 (16 i-subgroups)
// ---------------------------------------------------------------------------
__global__ __launch_bounds__(256) void s_kernel(
    const float* __restrict__ x, const float* __restrict__ w,
    const float* __restrict__ cbuf, float* __restrict__ s_part)
{
    __shared__ float4 x_lds4[8*128];   // [bb][ii][c] = 8*64*8 floats
    __shared__ float4 c_lds4[128];     // [bb][ii]    = 8*64 floats
    __shared__ float  red[16*16*8];    // [ig][o][bb]
    float* x_lds = (float*)x_lds4;
    float* c_lds = (float*)c_lds4;

    const int t  = threadIdx.x;
    const int k  = blockIdx.x >> 5;
    const int b0 = (blockIdx.x & 31) * 8;
    const int p  = blockIdx.y;
    const int o  = t & 15, ig = t >> 4;

    float acc[8];
#pragma unroll
    for (int bb = 0; bb < 8; bb++) acc[bb] = 0.f;

    const int i_beg = p * 384;
    for (int i0 = i_beg; i0 < i_beg + 384; i0 += 64) {
        __syncthreads();
        // stage x[b0..b0+8][i0..i0+64][0..8] -> 1024 float4
#pragma unroll
        for (int r = 0; r < 4; r++) {
            int lin = r * 256 + t;
            int bb  = lin >> 7;
            x_lds4[lin] = ((const float4*)(x + ((size_t)(b0 + bb) * I_ + i0) * C_))[lin & 127];
        }
        if (cbuf && t < 128) {
            int bb = t >> 4;
            c_lds4[t] = ((const float4*)(cbuf + ((size_t)(b0 + bb) * K_ + k) * I_ + i0))[t & 15];
        }
        __syncthreads();
#pragma unroll
        for (int j = 0; j < 4; j++) {
            const int ii = j * 16 + ig;
            const int i  = i0 + ii;
            const float4* wp = (const float4*)(w + (((size_t)k * I_ + i) * O_ + o) * C_);
            float4 w0 = wp[0], w1 = wp[1];
#pragma unroll
            for (int bb = 0; bb < 8; bb++) {
                const float4* xp = (const float4*)&x_lds[(bb * 64 + ii) * 8];
                float4 x0 = xp[0], x1 = xp[1];
                float u = w0.x*x0.x + w0.y*x0.y + w0.z*x0.z + w0.w*x0.w
                        + w1.x*x1.x + w1.y*x1.y + w1.z*x1.z + w1.w*x1.w;
                float cc = cbuf ? c_lds[bb * 64 + ii] : 1.0f;
                acc[bb] = fmaf(cc, u, acc[bb]);
            }
        }
    }
    __syncthreads();
#pragma unroll
    for (int bb = 0; bb < 8; bb++) red[(ig * 16 + o) * 8 + bb] = acc[bb];
    __syncthreads();
    if (t < 128) {
        const int bb = t >> 4, oo = t & 15;
        float ssum = 0.f;
#pragma unroll
        for (int g = 0; g < 16; g++) ssum += red[(g * 16 + oo) * 8 + bb];
        if (!cbuf) ssum *= (1.0f / K_);
        s_part[(size_t)p * BKO + ((size_t)(b0 + bb) * K_ + k) * O_ + oo] = ssum;
    }
}

// ---------------------------------------------------------------------------
// coeff_kernel: logits l[b,k,i] = sum_o (sum_c w[k,i,o,c] x[b,i,c]) * v[b,k,o]
//               c[b,k,i] = softmax_k(l)
// grid: (288, 4); block 256: bL = t>>2, iL = t&3 ; b = y*64+bL, i = x*4+iL
// ---------------------------------------------------------------------------
__global__ __launch_bounds__(256) void coeff_kernel(
    const float* __restrict__ x, const float* __restrict__ w,
    const float* __restrict__ v, float* __restrict__ cbuf)
{
    const int t  = threadIdx.x;
    const int b  = blockIdx.y * 64 + (t >> 2);
    const int i  = blockIdx.x * 4 + (t & 3);

    const float4* xp = (const float4*)(x + ((size_t)b * I_ + i) * C_);
    float4 x0 = xp[0], x1 = xp[1];

    float l[K_];
#pragma unroll
    for (int k = 0; k < K_; k++) {
        const float4* wp = (const float4*)(w + (((size_t)k * I_ + i) * O_) * C_);
        const float4* vp = (const float4*)(v + ((size_t)b * K_ + k) * O_);
        float4 va = vp[0], vb = vp[1], vc = vp[2], vd = vp[3];
        float vv[16] = {va.x,va.y,va.z,va.w, vb.x,vb.y,vb.z,vb.w,
                        vc.x,vc.y,vc.z,vc.w, vd.x,vd.y,vd.z,vd.w};
        float lk = 0.f;
#pragma unroll
        for (int oo = 0; oo < O_; oo++) {
            float4 w0 = wp[oo*2], w1 = wp[oo*2+1];
            float u = w0.x*x0.x + w0.y*x0.y + w0.z*x0.z + w0.w*x0.w
                    + w1.x*x1.x + w1.y*x1.y + w1.z*x1.z + w1.w*x1.w;
            lk = fmaf(u, vv[oo], lk);
        }
        l[k] = lk;
    }
    float m = l[0];
#pragma unroll
    for (int k = 1; k < K_; k++) m = fmaxf(m, l[k]);
    float e[K_]; float Z = 0.f;
#pragma unroll
    for (int k = 0; k < K_; k++) { e[k] = __expf(l[k] - m); Z += e[k]; }
    const float inv = 1.0f / Z;
#pragma unroll
    for (int k = 0; k < K_; k++)
        cbuf[((size_t)b * K_ + k) * I_ + i] = e[k] * inv;
}

// ---------------------------------------------------------------------------
// squash_kernel: s = sum of 3 partials; v = squash(s)
// mode 0: v_out = v, vacc = v     (after pass 1)
// mode 1: v_out = v, vacc += v    (after pass 2)
// mode 2: v_out = v only          (final, v_out = d_out)
// grid 160 x 256 threads, one thread per (b,k,o); 16-lane shuffle reduce
// ---------------------------------------------------------------------------
__global__ __launch_bounds__(256) void squash_kernel(
    const float* __restrict__ s_part, float* __restrict__ v_out,
    float* __restrict__ vacc, int mode)
{
    const int g = blockIdx.x * 256 + threadIdx.x;   // [b][k][o] linear
    float sv = s_part[g] + s_part[BKO + g] + s_part[2 * BKO + g];
    float n2 = sv * sv;
    n2 += __shfl_xor(n2, 1);
    n2 += __shfl_xor(n2, 2);
    n2 += __shfl_xor(n2, 4);
    n2 += __shfl_xor(n2, 8);
    const float norm  = sqrtf(n2);
    const float scale = n2 / (1.0f + n2) / (norm + 1e-9f);
    const float vv = scale * sv;
    v_out[g] = vv;
    if (mode == 0)      vacc[g] = vv;
    else if (mode == 1) vacc[g] = vacc[g] + vv;
}

// ---------------------------------------------------------------------------
extern "C" void kernel_launch(void* const* d_in, const int* in_sizes, int n_in,
                              void* d_out, int out_size, void* d_ws, size_t ws_size,
                              hipStream_t stream)
{
    const float* x = (const float*)d_in[0];
    const float* w = (const float*)d_in[1];

    float* c_buf = (float*)d_ws;                       // B*K*I      = 2,949,120 f
    float* s_buf = c_buf + (size_t)B_ * K_ * I_;       // 3 * BKO    partials
    float* v_buf = s_buf + (size_t)3 * BKO;            // BKO
    float* vacc  = v_buf + BKO;                        // BKO
    float* outp  = (float*)d_out;

    dim3 sgrid(320, 3), cgrid(288, 4);

    // pass 1: uniform c
    s_kernel<<<sgrid, 256, 0, stream>>>(x, w, nullptr, s_buf);
    squash_kernel<<<160, 256, 0, stream>>>(s_buf, v_buf, vacc, 0);   // v1, vacc=v1
    // pass 2: b = uv(v1)
    coeff_kernel<<<cgrid, 256, 0, stream>>>(x, w, v_buf, c_buf);
    s_kernel<<<sgrid, 256, 0, stream>>>(x, w, c_buf, s_buf);
    squash_kernel<<<160, 256, 0, stream>>>(s_buf, v_buf, vacc, 1);   // v2, vacc=v1+v2
    // pass 3 (final): b = uv(v1)+uv(v2) = uv(v1+v2)
    coeff_kernel<<<cgrid, 256, 0, stream>>>(x, w, vacc, c_buf);
    s_kernel<<<sgrid, 256, 0, stream>>>(x, w, c_buf, s_buf);
    squash_kernel<<<160, 256, 0, stream>>>(s_buf, outp, nullptr, 2);
}

// Round 2
// 238.988 us; speedup vs baseline: 2.4757x; 2.4757x over previous
//
#include <hip/hip_runtime.h>

#define B_ 256
#define K_ 10
#define I_ 1152
#define O_ 16
#define C_ 8
#define BKO (B_*K_*O_)   // 40960

static __device__ __forceinline__ unsigned short f32_bf16(float f) {
    unsigned int u = __float_as_uint(f);
    u += 0x7FFFu + ((u >> 16) & 1u);           // round-to-nearest-even
    return (unsigned short)(u >> 16);
}
static __device__ __forceinline__ float bf16_f32(unsigned short s) {
    return __uint_as_float(((unsigned int)s) << 16);
}

// ===========================================================================
// NEW PATH
// ===========================================================================

// ---------------------------------------------------------------------------
// uhat_kernel: u[b][k][i][o] = bf16( sum_c w[k,i,o,c] * x[b,i,c] )
// grid (72, 16): i0 = x*16, b0 = y*16.  256 thr: i_l = t&15, b_l = t>>4.
// w slab per k staged in LDS (row stride 132 floats -> 2-way-max conflicts,
// free per m136). x per thread in 8 regs. Stores: 32 B contiguous per thread.
// ---------------------------------------------------------------------------
__global__ __launch_bounds__(256) void uhat_kernel(
    const float* __restrict__ x, const float* __restrict__ w,
    unsigned short* __restrict__ u)
{
    __shared__ float w_lds[16 * 132];   // [ii][o*8+c], padded row stride 132
    const int t   = threadIdx.x;
    const int i_l = t & 15, b_l = t >> 4;
    const int i0  = blockIdx.x * 16;
    const int b   = blockIdx.y * 16 + b_l;
    const int i   = i0 + i_l;

    const float4* xp = (const float4*)(x + ((size_t)b * I_ + i) * C_);
    const float4 x0 = xp[0], x1 = xp[1];

    for (int k = 0; k < K_; k++) {
        __syncthreads();
        const float4* ws = (const float4*)(w + ((size_t)k * I_ + i0) * O_ * C_);
#pragma unroll
        for (int r = 0; r < 2; r++) {
            int idx = r * 256 + t;               // float4 index within 16x128 slab
            int ii = idx >> 5, rem = idx & 31;
            *(float4*)&w_lds[ii * 132 + rem * 4] = ws[idx];
        }
        __syncthreads();

        unsigned int pk[8];
#pragma unroll
        for (int oo = 0; oo < 8; oo++) {
            float uo2[2];
#pragma unroll
            for (int h = 0; h < 2; h++) {
                const int o = oo * 2 + h;
                const float4 w0 = *(const float4*)&w_lds[i_l * 132 + o * 8];
                const float4 w1 = *(const float4*)&w_lds[i_l * 132 + o * 8 + 4];
                uo2[h] = w0.x*x0.x + w0.y*x0.y + w0.z*x0.z + w0.w*x0.w
                       + w1.x*x1.x + w1.y*x1.y + w1.z*x1.z + w1.w*x1.w;
            }
            pk[oo] = (unsigned int)f32_bf16(uo2[0]) |
                     ((unsigned int)f32_bf16(uo2[1]) << 16);
        }
        unsigned int* dst = (unsigned int*)(u + (((size_t)b * K_ + k) * I_ + i) * O_);
        *(uint4*)(dst)     = make_uint4(pk[0], pk[1], pk[2], pk[3]);
        *(uint4*)(dst + 4) = make_uint4(pk[4], pk[5], pk[6], pk[7]);
    }
}

// ---------------------------------------------------------------------------
// route_kernel: one routing pass over materialized u_hat.
//   if !uniform: l[k] = sum_o u[b,k,i,o]*v[b,k,o]; c = softmax_k(l); else c=1/K
//   s_part[p][b][k][o] = sum_{i in part p} c[b,k,i]*u[b,k,i,o]
// grid (3, 256): p = i-partition (384 i's), b = batch.  256 thr: og=t&3 (o-quad),
// i_l = t>>2.  Coalesced 512 B/wave u loads; bf16 fragment kept in regs for
// both phases; shuffle-tree reduction over i lanes.
// ---------------------------------------------------------------------------
__global__ __launch_bounds__(256) void route_kernel(
    const unsigned short* __restrict__ u, const float* __restrict__ v,
    float* __restrict__ s_part, int uniform)
{
    __shared__ float v_lds[160];
    __shared__ float red[4 * 160];
    const int t  = threadIdx.x;
    const int og = t & 3, i_l = t >> 2;
    const int p  = blockIdx.x, b = blockIdx.y;

    if (!uniform && t < 160) v_lds[t] = v[(size_t)b * 160 + t];
    __syncthreads();

    float acc[K_][4];
#pragma unroll
    for (int k = 0; k < K_; k++)
#pragma unroll
        for (int j = 0; j < 4; j++) acc[k][j] = 0.f;

    for (int ic = 0; ic < 6; ic++) {
        const int i = p * 384 + ic * 64 + i_l;
        const unsigned short* ub =
            u + ((size_t)b * K_ * I_ + i) * O_ + og * 4;

        ushort4 us[K_];
        float   c[K_];
        if (!uniform) {
            float l[K_];
#pragma unroll
            for (int k = 0; k < K_; k++) {
                us[k] = *(const ushort4*)(ub + (size_t)k * I_ * O_);
                const float* vk = &v_lds[k * 16 + og * 4];
                float part = bf16_f32(us[k].x) * vk[0]
                           + bf16_f32(us[k].y) * vk[1]
                           + bf16_f32(us[k].z) * vk[2]
                           + bf16_f32(us[k].w) * vk[3];
                part += __shfl_xor(part, 1);
                part += __shfl_xor(part, 2);
                l[k] = part;
            }
            float m = l[0];
#pragma unroll
            for (int k = 1; k < K_; k++) m = fmaxf(m, l[k]);
            float Z = 0.f;
#pragma unroll
            for (int k = 0; k < K_; k++) { c[k] = __expf(l[k] - m); Z += c[k]; }
            const float inv = 1.0f / Z;
#pragma unroll
            for (int k = 0; k < K_; k++) c[k] *= inv;
        } else {
#pragma unroll
            for (int k = 0; k < K_; k++) {
                us[k] = *(const ushort4*)(ub + (size_t)k * I_ * O_);
                c[k] = 1.0f;   // scaled by 1/K at write-out
            }
        }
#pragma unroll
        for (int k = 0; k < K_; k++) {
            acc[k][0] = fmaf(c[k], bf16_f32(us[k].x), acc[k][0]);
            acc[k][1] = fmaf(c[k], bf16_f32(us[k].y), acc[k][1]);
            acc[k][2] = fmaf(c[k], bf16_f32(us[k].z), acc[k][2]);
            acc[k][3] = fmaf(c[k], bf16_f32(us[k].w), acc[k][3]);
        }
    }

    // reduce over the 16 i-lanes within each wave (lane = (i_l&15)*4 + og)
#pragma unroll
    for (int k = 0; k < K_; k++)
#pragma unroll
        for (int j = 0; j < 4; j++) {
            float a = acc[k][j];
            a += __shfl_xor(a, 4);
            a += __shfl_xor(a, 8);
            a += __shfl_xor(a, 16);
            a += __shfl_xor(a, 32);
            acc[k][j] = a;
        }
    const int lane = t & 63, wv = t >> 6;
    if ((lane & 0x3C) == 0) {   // lanes 0..3 hold wave sums
#pragma unroll
        for (int k = 0; k < K_; k++)
#pragma unroll
            for (int j = 0; j < 4; j++)
                red[wv * 160 + k * 16 + og * 4 + j] = acc[k][j];
    }
    __syncthreads();
    if (t < 160) {
        float s = red[t] + red[160 + t] + red[320 + t] + red[480 + t];
        if (uniform) s *= (1.0f / K_);
        const int k = t >> 4, o = t & 15;
        s_part[(size_t)p * BKO + ((size_t)b * K_ + k) * O_ + o] = s;
    }
}

// ---------------------------------------------------------------------------
// squash_kernel: s = sum of 3 partials; v = squash(s)
// mode 0: v_out=v, vacc=v | mode 1: v_out=v, vacc+=v | mode 2: v_out=v only
// ---------------------------------------------------------------------------
__global__ __launch_bounds__(256) void squash_kernel(
    const float* __restrict__ s_part, float* __restrict__ v_out,
    float* __restrict__ vacc, int mode)
{
    const int g = blockIdx.x * 256 + threadIdx.x;   // [b][k][o] linear
    float sv = s_part[g] + s_part[BKO + g] + s_part[2 * BKO + g];
    float n2 = sv * sv;
    n2 += __shfl_xor(n2, 1);
    n2 += __shfl_xor(n2, 2);
    n2 += __shfl_xor(n2, 4);
    n2 += __shfl_xor(n2, 8);
    const float norm  = sqrtf(n2);
    const float scale = n2 / (1.0f + n2) / (norm + 1e-9f);
    const float vv = scale * sv;
    v_out[g] = vv;
    if (mode == 0)      vacc[g] = vv;
    else if (mode == 1) vacc[g] = vacc[g] + vv;
}

// ===========================================================================
// FALLBACK PATH (round-1 kernels, used only if ws_size too small)
// ===========================================================================
__global__ __launch_bounds__(256) void s_kernel(
    const float* __restrict__ x, const float* __restrict__ w,
    const float* __restrict__ cbuf, float* __restrict__ s_part)
{
    __shared__ float4 x_lds4[8*128];
    __shared__ float4 c_lds4[128];
    __shared__ float  red[16*16*8];
    float* x_lds = (float*)x_lds4;
    float* c_lds = (float*)c_lds4;

    const int t  = threadIdx.x;
    const int k  = blockIdx.x >> 5;
    const int b0 = (blockIdx.x & 31) * 8;
    const int p  = blockIdx.y;
    const int o  = t & 15, ig = t >> 4;

    float acc[8];
#pragma unroll
    for (int bb = 0; bb < 8; bb++) acc[bb] = 0.f;

    const int i_beg = p * 384;
    for (int i0 = i_beg; i0 < i_beg + 384; i0 += 64) {
        __syncthreads();
#pragma unroll
        for (int r = 0; r < 4; r++) {
            int lin = r * 256 + t;
            int bb  = lin >> 7;
            x_lds4[lin] = ((const float4*)(x + ((size_t)(b0 + bb) * I_ + i0) * C_))[lin & 127];
        }
        if (cbuf && t < 128) {
            int bb = t >> 4;
            c_lds4[t] = ((const float4*)(cbuf + ((size_t)(b0 + bb) * K_ + k) * I_ + i0))[t & 15];
        }
        __syncthreads();
#pragma unroll
        for (int j = 0; j < 4; j++) {
            const int ii = j * 16 + ig;
            const int i  = i0 + ii;
            const float4* wp = (const float4*)(w + (((size_t)k * I_ + i) * O_ + o) * C_);
            float4 w0 = wp[0], w1 = wp[1];
#pragma unroll
            for (int bb = 0; bb < 8; bb++) {
                const float4* xp = (const float4*)&x_lds[(bb * 64 + ii) * 8];
                float4 x0 = xp[0], x1 = xp[1];
                float uu = w0.x*x0.x + w0.y*x0.y + w0.z*x0.z + w0.w*x0.w
                         + w1.x*x1.x + w1.y*x1.y + w1.z*x1.z + w1.w*x1.w;
                float cc = cbuf ? c_lds[bb * 64 + ii] : 1.0f;
                acc[bb] = fmaf(cc, uu, acc[bb]);
            }
        }
    }
    __syncthreads();
#pragma unroll
    for (int bb = 0; bb < 8; bb++) red[(ig * 16 + o) * 8 + bb] = acc[bb];
    __syncthreads();
    if (t < 128) {
        const int bb = t >> 4, oo = t & 15;
        float ssum = 0.f;
#pragma unroll
        for (int g2 = 0; g2 < 16; g2++) ssum += red[(g2 * 16 + oo) * 8 + bb];
        if (!cbuf) ssum *= (1.0f / K_);
        s_part[(size_t)p * BKO + ((size_t)(b0 + bb) * K_ + k) * O_ + oo] = ssum;
    }
}

__global__ __launch_bounds__(256) void coeff_kernel(
    const float* __restrict__ x, const float* __restrict__ w,
    const float* __restrict__ v, float* __restrict__ cbuf)
{
    const int t  = threadIdx.x;
    const int b  = blockIdx.y * 64 + (t >> 2);
    const int i  = blockIdx.x * 4 + (t & 3);

    const float4* xp = (const float4*)(x + ((size_t)b * I_ + i) * C_);
    float4 x0 = xp[0], x1 = xp[1];

    float l[K_];
#pragma unroll
    for (int k = 0; k < K_; k++) {
        const float4* wp = (const float4*)(w + (((size_t)k * I_ + i) * O_) * C_);
        const float4* vp = (const float4*)(v + ((size_t)b * K_ + k) * O_);
        float4 va = vp[0], vb = vp[1], vc = vp[2], vd = vp[3];
        float vv[16] = {va.x,va.y,va.z,va.w, vb.x,vb.y,vb.z,vb.w,
                        vc.x,vc.y,vc.z,vc.w, vd.x,vd.y,vd.z,vd.w};
        float lk = 0.f;
#pragma unroll
        for (int oo = 0; oo < O_; oo++) {
            float4 w0 = wp[oo*2], w1 = wp[oo*2+1];
            float uu = w0.x*x0.x + w0.y*x0.y + w0.z*x0.z + w0.w*x0.w
                     + w1.x*x1.x + w1.y*x1.y + w1.z*x1.z + w1.w*x1.w;
            lk = fmaf(uu, vv[oo], lk);
        }
        l[k] = lk;
    }
    float m = l[0];
#pragma unroll
    for (int k = 1; k < K_; k++) m = fmaxf(m, l[k]);
    float e[K_]; float Z = 0.f;
#pragma unroll
    for (int k = 0; k < K_; k++) { e[k] = __expf(l[k] - m); Z += e[k]; }
    const float inv = 1.0f / Z;
#pragma unroll
    for (int k = 0; k < K_; k++)
        cbuf[((size_t)b * K_ + k) * I_ + i] = e[k] * inv;
}

// ===========================================================================
extern "C" void kernel_launch(void* const* d_in, const int* in_sizes, int n_in,
                              void* d_out, int out_size, void* d_ws, size_t ws_size,
                              hipStream_t stream)
{
    const float* x = (const float*)d_in[0];
    const float* w = (const float*)d_in[1];
    float* outp = (float*)d_out;

    const size_t need = (size_t)5 * BKO * 4 + (size_t)B_ * K_ * I_ * O_ * 2;

    if (ws_size >= need) {
        float* s_buf = (float*)d_ws;                 // 3*BKO
        float* v_buf = s_buf + (size_t)3 * BKO;      // BKO
        float* vacc  = s_buf + (size_t)4 * BKO;      // BKO
        unsigned short* u = (unsigned short*)(s_buf + (size_t)5 * BKO);

        uhat_kernel<<<dim3(72, 16), 256, 0, stream>>>(x, w, u);
        // pass 1: uniform c
        route_kernel<<<dim3(3, 256), 256, 0, stream>>>(u, nullptr, s_buf, 1);
        squash_kernel<<<160, 256, 0, stream>>>(s_buf, v_buf, vacc, 0);
        // pass 2: b = uv(v1)
        route_kernel<<<dim3(3, 256), 256, 0, stream>>>(u, v_buf, s_buf, 0);
        squash_kernel<<<160, 256, 0, stream>>>(s_buf, v_buf, vacc, 1);
        // pass 3 (final): b = uv(v1)+uv(v2) = uv(v1+v2)
        route_kernel<<<dim3(3, 256), 256, 0, stream>>>(u, vacc, s_buf, 0);
        squash_kernel<<<160, 256, 0, stream>>>(s_buf, outp, nullptr, 2);
    } else {
        // round-1 fallback
        float* c_buf = (float*)d_ws;
        float* s_buf = c_buf + (size_t)B_ * K_ * I_;
        float* v_buf = s_buf + (size_t)3 * BKO;
        float* vacc  = v_buf + BKO;

        dim3 sgrid(320, 3), cgrid(288, 4);
        s_kernel<<<sgrid, 256, 0, stream>>>(x, w, nullptr, s_buf);
        squash_kernel<<<160, 256, 0, stream>>>(s_buf, v_buf, vacc, 0);
        coeff_kernel<<<cgrid, 256, 0, stream>>>(x, w, v_buf, c_buf);
        s_kernel<<<sgrid, 256, 0, stream>>>(x, w, c_buf, s_buf);
        squash_kernel<<<160, 256, 0, stream>>>(s_buf, v_buf, vacc, 1);
        coeff_kernel<<<cgrid, 256, 0, stream>>>(x, w, vacc, c_buf);
        s_kernel<<<sgrid, 256, 0, stream>>>(x, w, c_buf, s_buf);
        squash_kernel<<<160, 256, 0, stream>>>(s_buf, outp, nullptr, 2);
    }
}